// Round 4
// baseline (102.368 us; speedup 1.0000x reference)
//
#include <hip/hip_runtime.h>

// PNNLayer — exact reference semantics:
//   self_feature[n,a,:] = embeds[(32n + a) mod 50000]   (tile/reshape scramble)
//   out[n,k] = b[k] + Σ_a dists[a,n]·M1[a,k] + SBW[(2n)%3125, k]
//   M1[a,k]  = (1/32)·emb[aid[a]]·W1[k,:]
//   SBW[i,k] = (1/32)·(Σ_{j<32} emb[(16i+j)%N])·W2[k,:]   (only 3125 distinct)
// Kernel time floor: 32 MB HBM traffic ≈ 5 µs; measured window is dominated by
// harness re-poison fills (2×256 MB @ ~43 µs, see rocprof top-5 in R2).

typedef float f32x4 __attribute__((ext_vector_type(4)));   // native vec for nontemporal builtins

constexpr int N_PTS  = 50000;
constexpr int A_ANCH = 32;
constexpr int D_DIM  = 64;
constexpr int NSB    = 3125;             // distinct self-feature blocks
constexpr int TN     = 16;               // n-rows per tile (main)
constexpr int TILES  = N_PTS / TN;       // 3125
constexpr int XSTR   = 36;               // 32 + 4 pad, float4-aligned
constexpr int PREP_TILE   = 8;           // i's per prep block
constexpr int PREP_BLOCKS = (NSB + PREP_TILE - 1) / PREP_TILE;   // 391
constexpr int MAIN_GRID   = 782;         // ceil(3125/4) → 4 tiles/block

// ---- prep: blocks 0..390 -> SBW tiles; block 391 -> M1 ----
__global__ __launch_bounds__(256) void prep_kernel(
        const float* __restrict__ embeds,
        const int*   __restrict__ aid,
        const float* __restrict__ W,      // (64,128)
        float*       __restrict__ M1,     // (32,64)
        float*       __restrict__ SBW)    // (3125,64)
{
    const int t = threadIdx.x;

    if (blockIdx.x == PREP_BLOCKS) {
        // M1[a,k] = (1/32) * Σ_d embeds[aid[a],d] * W[k*128 + d]
        for (int idx = t; idx < A_ANCH * D_DIM; idx += 256) {
            int a = idx >> 6, k = idx & 63;
            const float* erow = embeds + (size_t)aid[a] * D_DIM;   // broadcast in-wave
            const float* wrow = W + (size_t)k * 128;
            float s = 0.0f;
#pragma unroll
            for (int d = 0; d < D_DIM; ++d) s += erow[d] * wrow[d];
            M1[idx] = s * (1.0f / 32.0f);
        }
        return;
    }

    __shared__ float w2[64 * 64];          // w2[d*64+k] = W[k*128+64+d]
    __shared__ float sb[PREP_TILE * 64];   // sb[il*64+d]

    {   // stage W2^T; per-instr LDS writes are 64 contiguous floats (conflict-free)
        int k  = t & 63;
        int d0 = (t >> 6) * 16;
        const float* wr = W + (size_t)k * 128 + 64;
#pragma unroll
        for (int q = 0; q < 16; ++q) w2[(d0 + q) * 64 + k] = wr[d0 + q];
    }

    const int i0 = blockIdx.x * PREP_TILE;
    {   // block sums: sb[il,d] = Σ_j embeds[(16(i0+il)+j) % N, d]; rows = 256 B coalesced
        int d = t & 63, il = t >> 6;
        for (; il < PREP_TILE; il += 4) {
            int i = i0 + il;
            if (i >= NSB) break;           // i increases with il -> break safe
            int base = 16 * i;
            float s = 0.0f;
#pragma unroll
            for (int j = 0; j < 32; ++j) {
                int r = base + j;
                if (r >= N_PTS) r -= N_PTS;
                s += embeds[(size_t)r * D_DIM + d];
            }
            sb[il * 64 + d] = s;
        }
    }
    __syncthreads();
    {   // SBW[i,k] = (1/32) Σ_d sb[il,d]*w2[d,k]; sb broadcast, w2 contiguous
        int k = t & 63, il = t >> 6;
        for (; il < PREP_TILE; il += 4) {
            int i = i0 + il;
            if (i >= NSB) break;
            const float* srow = sb + il * 64;
            float s = 0.0f;
#pragma unroll
            for (int d = 0; d < D_DIM; ++d) s += srow[d] * w2[d * 64 + k];
            SBW[(size_t)i * 64 + k] = s * (1.0f / 32.0f);
        }
    }
}

// ---- main: out[n,k] = b[k] + Σ_a dists[a,n]·M1[a,k] + SBW[(2n)%3125, k] ----
// lane map: t&15 -> k-quad (k0=4*(t&15)), t>>4 -> n_local (4 n x 16 kq per wave)
// Double-buffered dists tile -> one barrier per tile.
__global__ __launch_bounds__(256, 4) void pnn_main(
        const float* __restrict__ dists,   // (32, N)
        const float* __restrict__ b,       // (64,)
        const float* __restrict__ M1,      // (32,64)
        const float* __restrict__ SBW,     // (3125,64)
        float*       __restrict__ out)     // (N,64)
{
    __shared__ float m1s[A_ANCH * D_DIM];  // 8 KB
    __shared__ float xs[2][TN * XSTR];     // 2 x 2.25 KB dists tiles

    const int t = threadIdx.x;

    {   // stage M1: 512 float4, 2/thread, coalesced
        const float4* M4 = (const float4*)M1;
        float4*       s4 = (float4*)m1s;
#pragma unroll
        for (int q = 0; q < 2; ++q) s4[t + 256 * q] = M4[t + 256 * q];
    }

    const int lane_k  = t & 15;
    const int n_local = t >> 4;
    const int k0      = lane_k * 4;
    const float4 bias = *(const float4*)(b + k0);

    const int st_a  = t >> 4;          // staging: a index (0..15 then +16)
    const int st_nl = t & 15;          // staging: n_local

    // prologue: stage tile g=0 into xs[0]
    {
        const int n0 = blockIdx.x * TN;
#pragma unroll
        for (int q = 0; q < 2; ++q) {
            int a = st_a + 16 * q;
            xs[0][st_nl * XSTR + a] =
                __builtin_nontemporal_load(dists + (size_t)a * N_PTS + n0 + st_nl);
        }
    }
    __syncthreads();

    int tile = blockIdx.x;
    for (int g = 0; tile < TILES; ++g, tile += MAIN_GRID) {
        const int cur = g & 1;
        const int n   = tile * TN + n_local;
        const int i   = (2 * n) % NSB;
        float4 sbw = *(const float4*)(SBW + (size_t)i * D_DIM + k0);  // L2-resident

        // stage NEXT tile into the other buffer (no barrier needed: disjoint buf)
        const int ntile = tile + MAIN_GRID;
        if (ntile < TILES) {
            const int n0 = ntile * TN;
#pragma unroll
            for (int q = 0; q < 2; ++q) {
                int a = st_a + 16 * q;
                xs[cur ^ 1][st_nl * XSTR + a] =
                    __builtin_nontemporal_load(dists + (size_t)a * N_PTS + n0 + st_nl);
            }
        }

        float4 acc;
        acc.x = bias.x + sbw.x; acc.y = bias.y + sbw.y;
        acc.z = bias.z + sbw.z; acc.w = bias.w + sbw.w;

        const float* xrow = xs[cur] + n_local * XSTR;
#pragma unroll
        for (int jj = 0; jj < A_ANCH; jj += 4) {
            float4 xv = *(const float4*)(xrow + jj);
            float4 w0 = *(const float4*)(m1s + (jj + 0) * 64 + k0);
            float4 w1 = *(const float4*)(m1s + (jj + 1) * 64 + k0);
            float4 w2 = *(const float4*)(m1s + (jj + 2) * 64 + k0);
            float4 w3 = *(const float4*)(m1s + (jj + 3) * 64 + k0);
            acc.x += xv.x * w0.x; acc.y += xv.x * w0.y; acc.z += xv.x * w0.z; acc.w += xv.x * w0.w;
            acc.x += xv.y * w1.x; acc.y += xv.y * w1.y; acc.z += xv.y * w1.z; acc.w += xv.y * w1.w;
            acc.x += xv.z * w2.x; acc.y += xv.z * w2.y; acc.z += xv.z * w2.z; acc.w += xv.z * w2.w;
            acc.x += xv.w * w3.x; acc.y += xv.w * w3.y; acc.z += xv.w * w3.z; acc.w += xv.w * w3.w;
        }
        {   // nontemporal store via native vector type (builtin rejects HIP_vector_type)
            f32x4 accv;
            accv.x = acc.x; accv.y = acc.y; accv.z = acc.z; accv.w = acc.w;
            __builtin_nontemporal_store(accv, (f32x4*)(out + (size_t)n * D_DIM + k0));
        }

        __syncthreads();   // readers of xs[cur] done before it's re-staged next iter
    }
}

extern "C" void kernel_launch(void* const* d_in, const int* in_sizes, int n_in,
                              void* d_out, int out_size, void* d_ws, size_t ws_size,
                              hipStream_t stream) {
    const float* embeds = (const float*)d_in[0];   // (N, 64)
    const float* dists  = (const float*)d_in[1];   // (32, N)
    const int*   aid    = (const int*)  d_in[2];   // (32,)
    const float* W      = (const float*)d_in[3];   // (64, 128)
    const float* b      = (const float*)d_in[4];   // (64,)
    float*       out    = (float*)d_out;

    float* M1  = (float*)d_ws;                     // 2048 floats (8 KB)
    float* SBW = (float*)d_ws + A_ANCH * D_DIM;    // 3125*64 floats (800 KB)

    prep_kernel<<<PREP_BLOCKS + 1, 256, 0, stream>>>(embeds, aid, W, M1, SBW);
    pnn_main<<<MAIN_GRID, 256, 0, stream>>>(dists, b, M1, SBW, out);
}